// Round 1
// baseline (308.090 us; speedup 1.0000x reference)
//
#include <hip/hip_runtime.h>
#include <math.h>

#define MD 128
#define NA 2048
#define AS 512
#define NS 32768
#define NFFT 98304
#define NBE 512
#define EPB 8
#define TT 2048
#define RT 8
#define CT 256

__device__ __forceinline__ float lrelu(float v) { return v > 0.f ? v : 0.2f * v; }

// ---------------------------------------------------------------------------
// Kernel 1: per-(b,e) MLP stacks + gumbel argmax + filter/params build.
// time stack in fp64 (shift precision is critical: dNc = 32767*dtime).
// Writes: G[be][512] = (-1)^tau * atoms[idx][tau]*inv_norm * amp *
//                      (-1)^(m0+1)*sin(pi*frac)/NFFT,  m0s[be], fracs[be].
// ---------------------------------------------------------------------------
__global__ __launch_bounds__(128) void prep_kernel(
    const float* __restrict__ x, const float* __restrict__ times,
    const float* __restrict__ gu, const float* __restrict__ atoms,
    const float* __restrict__ tw0, const float* __restrict__ tb0,
    const float* __restrict__ tw1, const float* __restrict__ tb1,
    const float* __restrict__ tw2, const float* __restrict__ tb2,
    const float* __restrict__ sw0, const float* __restrict__ sb0,
    const float* __restrict__ sw1, const float* __restrict__ sb1,
    const float* __restrict__ sw2, const float* __restrict__ sb2,
    const float* __restrict__ aw0, const float* __restrict__ ab0,
    const float* __restrict__ aw1, const float* __restrict__ ab1,
    const float* __restrict__ aw2, const float* __restrict__ ab2,
    float* __restrict__ G, int* __restrict__ m0s, float* __restrict__ fracs)
{
  const int be = blockIdx.x;
  const int tid = threadIdx.x;
  __shared__ float xs[MD];
  __shared__ double dh[MD], dh2[MD], dred[128];
  __shared__ float h1[MD], h2[MD], red[128];
  __shared__ int redi[128];
  __shared__ float sc_time, sc_amp, sc_coef, sc_inv;
  __shared__ int sc_idx;

  xs[tid] = x[be * MD + tid];
  __syncthreads();

  // ---- time stack (fp64) ----
  {
    double s = (double)tb0[tid];
    for (int k = 0; k < MD; ++k) s += (double)xs[k] * (double)tw0[k * MD + tid];
    dh[tid] = s > 0.0 ? s : 0.2 * s;
    __syncthreads();
    double s2 = (double)tb1[tid];
    for (int k = 0; k < MD; ++k) s2 += dh[k] * (double)tw1[k * MD + tid];
    dh2[tid] = s2 > 0.0 ? s2 : 0.2 * s2;
    __syncthreads();
    dred[tid] = dh2[tid] * (double)tw2[tid];
    __syncthreads();
    for (int off = 64; off > 0; off >>= 1) {
      if (tid < off) dred[tid] += dred[tid + off];
      __syncthreads();
    }
    if (tid == 0) {
      double tval = dred[0] + (double)tb2[0];
      double sg = 1.0 / (1.0 + exp(-tval));
      float tf = (float)sg;                 // round like the fp32 reference
      sc_time = tf * 1.0f + times[be];      // FACTOR = 1
    }
    __syncthreads();
  }

  // ---- amp stack (fp32) ----
  {
    float s = ab0[tid];
    for (int k = 0; k < MD; ++k) s += xs[k] * aw0[k * MD + tid];
    h1[tid] = lrelu(s);
    __syncthreads();
    float s2 = ab1[tid];
    for (int k = 0; k < MD; ++k) s2 += h1[k] * aw1[k * MD + tid];
    h2[tid] = lrelu(s2);
    __syncthreads();
    red[tid] = h2[tid] * aw2[tid];
    __syncthreads();
    for (int off = 64; off > 0; off >>= 1) {
      if (tid < off) red[tid] += red[tid + off];
      __syncthreads();
    }
    if (tid == 0) {
      float av = red[0] + ab2[0];
      sc_amp = av * av;
    }
    __syncthreads();
  }

  // ---- selection stack (fp32) + gumbel argmax ----
  {
    float s = sb0[tid];
    for (int k = 0; k < MD; ++k) s += xs[k] * sw0[k * MD + tid];
    h1[tid] = lrelu(s);
    __syncthreads();
    float s2 = sb1[tid];
    for (int k = 0; k < MD; ++k) s2 += h1[k] * sw1[k * MD + tid];
    h2[tid] = lrelu(s2);
    __syncthreads();
    float best = -3.4e38f;
    int bi = 0;
    for (int o = tid; o < NA; o += 128) {
      float sv = sb2[o];
      for (int k = 0; k < MD; ++k) sv += h2[k] * sw2[k * NA + o];
      float u = gu[be * NA + o];
      float gv = -logf(-logf(u + 1e-10f) + 1e-10f);
      float v = sv + gv;                    // TAU = 1; softmax preserves argmax
      if (v > best) { best = v; bi = o; }
    }
    red[tid] = best; redi[tid] = bi;
    __syncthreads();
    for (int off = 64; off > 0; off >>= 1) {
      if (tid < off) {
        float ov = red[tid + off]; int oi = redi[tid + off];
        if (ov > red[tid] || (ov == red[tid] && oi < redi[tid])) { red[tid] = ov; redi[tid] = oi; }
      }
      __syncthreads();
    }
    if (tid == 0) sc_idx = redi[0];
    __syncthreads();
  }

  // ---- atom norm + shift params ----
  const int idx = sc_idx;
  {
    float ss = 0.f;
    for (int i = tid; i < AS; i += 128) { float v = atoms[idx * AS + i]; ss += v * v; }
    red[tid] = ss;
    __syncthreads();
    for (int off = 64; off > 0; off >>= 1) {
      if (tid < off) red[tid] += red[tid + off];
      __syncthreads();
    }
    if (tid == 0) {
      sc_inv = 1.f / (sqrtf(red[0]) + 1e-8f);
      // Nc = time * 16384 * 98304 / 49153  (effective sample shift)
      double Nc = (double)sc_time * (1610612736.0 / 49153.0);
      double rr = rint(Nc);
      int m0 = (int)rr;
      float fr = (float)(Nc - rr);
      if (fabsf(fr) < 1e-9f) fr = (fr < 0.f) ? -1e-9f : 1e-9f;  // avoid 0*inf
      m0s[be] = m0;
      fracs[be] = fr;
      sc_coef = sc_amp * ((m0 & 1) ? 1.0f : -1.0f) *
                sinf(3.14159265358979323846f * fr) * (1.0f / (float)NFFT);
    }
    __syncthreads();
  }

  const float cf = sc_coef * sc_inv;
  for (int t = tid; t < AS; t += 128) {
    float av = atoms[idx * AS + t] * cf;
    G[be * AS + t] = (t & 1) ? -av : av;
  }
}

// ---------------------------------------------------------------------------
// Kernel 2: y[b][t] = (-1)^t * sum_e sum_tau G[be][tau] * T_be[t - tau]
// where T_be[v] = cot(pi*((v - m0) - frac)/NFFT).
// Block: 2048 t-tile x 8 e's. cot table in LDS (XOR-swizzled float4 groups
// so the stride-8-float b128 window reads are bank-conflict-free).
// 8 outputs/thread, 16-float register sliding window (2 new b128 per 64 FMA).
// ---------------------------------------------------------------------------
__global__ __launch_bounds__(CT) void conv_kernel(
    const float* __restrict__ G, const int* __restrict__ m0s,
    const float* __restrict__ fracs, float* __restrict__ out)
{
  const int tile = blockIdx.x;   // 0..15
  const int b    = blockIdx.y;   // 0..7
  const int eg   = blockIdx.z;   // 0..7
  const int tid  = threadIdx.x;
  const int t0   = tile * TT;

  __shared__ float4 Tl4[640];    // 2560 floats, logical v = t0-511 .. t0+2047
  __shared__ float4 Gl4[128];    // 512-tap filter
  float* Tl = (float*)Tl4;
  float* Gl = (float*)Gl4;

  float acc[RT];
#pragma unroll
  for (int r = 0; r < RT; ++r) acc[r] = 0.f;

  for (int ei = 0; ei < EPB; ++ei) {
    const int be = b * 64 + eg * EPB + ei;
    __syncthreads();  // previous e's reads done before refill
    for (int i = tid; i < AS; i += CT) Gl[i] = G[be * AS + i];
    const int m0 = m0s[be];
    const float fr = fracs[be];
    for (int i = tid; i < 2559; i += CT) {
      int v = t0 - 511 + i;
      float w = (float)(v - m0) - fr;               // |w| <= ~66047, never 0
      float th = w * (float)(3.14159265358979323846 / 98304.0);  // |th| < 2.12
      float sn, cs;
      sincosf(th, &sn, &cs);
      float val = cs / sn;
      int g = i >> 2;
      int gs = g ^ ((g >> 3) & 1);                  // bank swizzle
      Tl[(gs << 2) | (i & 3)] = val;
    }
    __syncthreads();

    float Wf[16];
    {
      int g0 = 2 * tid;     float4 q0 = Tl4[g0 ^ ((g0 >> 3) & 1)];
      int g1 = 2 * tid + 1; float4 q1 = Tl4[g1 ^ ((g1 >> 3) & 1)];
      Wf[0] = q0.x; Wf[1] = q0.y; Wf[2] = q0.z; Wf[3] = q0.w;
      Wf[4] = q1.x; Wf[5] = q1.y; Wf[6] = q1.z; Wf[7] = q1.w;
    }
#pragma unroll
    for (int k = 0; k < 64; ++k) {
      const int gA = 2 * tid + 2 * k + 2;
      const int gB = gA + 1;
      float4 qa = Tl4[gA ^ ((gA >> 3) & 1)];
      float4 qb = Tl4[gB ^ ((gB >> 3) & 1)];
      Wf[8]  = qa.x; Wf[9]  = qa.y; Wf[10] = qa.z; Wf[11] = qa.w;
      Wf[12] = qb.x; Wf[13] = qb.y; Wf[14] = qb.z; Wf[15] = qb.w;
      const int tc = 504 - 8 * k;
      const float4 gq0 = Gl4[tc >> 2];
      const float4 gq1 = Gl4[(tc >> 2) + 1];
      const float gvals[8] = {gq0.x, gq0.y, gq0.z, gq0.w,
                              gq1.x, gq1.y, gq1.z, gq1.w};
      // acc[r] += G[tc+d] * Tl[tid*8 + 8k + 7 + r - d]
#pragma unroll
      for (int d = 0; d < 8; ++d) {
        const float gv = gvals[d];
#pragma unroll
        for (int r = 0; r < RT; ++r)
          acc[r] = fmaf(gv, Wf[7 + r - d], acc[r]);
      }
#pragma unroll
      for (int m = 0; m < 8; ++m) Wf[m] = Wf[m + 8];
    }
  }

  const int tbase = t0 + tid * RT;
#pragma unroll
  for (int r = 0; r < RT; ++r) {
    float v = (r & 1) ? -acc[r] : acc[r];   // (-1)^t, t0 and tid*8 even
    atomicAdd(&out[b * NS + tbase + r], v);
  }
}

// ---------------------------------------------------------------------------
extern "C" void kernel_launch(void* const* d_in, const int* in_sizes, int n_in,
                              void* d_out, int out_size, void* d_ws, size_t ws_size,
                              hipStream_t stream) {
  const float* x     = (const float*)d_in[0];
  const float* times = (const float*)d_in[1];
  const float* gu    = (const float*)d_in[2];
  const float* atoms = (const float*)d_in[3];
  const float* tw0 = (const float*)d_in[4];  const float* tb0 = (const float*)d_in[5];
  const float* tw1 = (const float*)d_in[6];  const float* tb1 = (const float*)d_in[7];
  const float* tw2 = (const float*)d_in[8];  const float* tb2 = (const float*)d_in[9];
  const float* sw0 = (const float*)d_in[10]; const float* sb0 = (const float*)d_in[11];
  const float* sw1 = (const float*)d_in[12]; const float* sb1 = (const float*)d_in[13];
  const float* sw2 = (const float*)d_in[14]; const float* sb2 = (const float*)d_in[15];
  const float* aw0 = (const float*)d_in[16]; const float* ab0 = (const float*)d_in[17];
  const float* aw1 = (const float*)d_in[18]; const float* ab1 = (const float*)d_in[19];
  const float* aw2 = (const float*)d_in[20]; const float* ab2 = (const float*)d_in[21];

  // ws layout: G (512*512 f32) | m0s (512 i32) | fracs (512 f32)  ~1.05 MB
  float* G     = (float*)d_ws;
  int*   m0s   = (int*)((char*)d_ws + (size_t)NBE * AS * sizeof(float));
  float* fracs = (float*)((char*)d_ws + (size_t)NBE * AS * sizeof(float) + NBE * sizeof(int));

  hipMemsetAsync(d_out, 0, (size_t)out_size * sizeof(float), stream);

  prep_kernel<<<NBE, 128, 0, stream>>>(x, times, gu, atoms,
                                       tw0, tb0, tw1, tb1, tw2, tb2,
                                       sw0, sb0, sw1, sb1, sw2, sb2,
                                       aw0, ab0, aw1, ab1, aw2, ab2,
                                       G, m0s, fracs);

  conv_kernel<<<dim3(NS / TT, 8, 64 / EPB), CT, 0, stream>>>(G, m0s, fracs, (float*)d_out);
}